// Round 1
// baseline (575.099 us; speedup 1.0000x reference)
//
#include <hip/hip_runtime.h>

namespace {
constexpr int kN = 8192, kV = 8, kO = 16, kH = 128;
constexpr float kStep = 2.0f;
constexpr float kDistCost = 1.0f, kObstCost = 0.1f, kObstRadius = 1.0f;
constexpr float kVehCost = 0.1f, kVehRadius = 1.0f;
constexpr int kInRow = 4 * kV + 3 * kO;  // 80 floats per n
}  // namespace

// One block (1024 threads) per n. Thread tid = v*128 + h.
__global__ __launch_bounds__(1024) void loss_main(
    const float* __restrict__ pred, const float* __restrict__ inputs,
    float* __restrict__ accf, unsigned int* __restrict__ accu) {
  const int n = blockIdx.x;
  const int tid = threadIdx.x;
  const int v = tid >> 7;
  const int h = tid & (kH - 1);
  const int lane = tid & 63;

  __shared__ float sh_in[kInRow];
  __shared__ float sh_ox[kO], sh_oy[kO], sh_orr2[kO];
  __shared__ float2 sh_traj[kV * kH];
  __shared__ float sh_wc[kV], sh_ws[kV];
  __shared__ float sh_bs1, sh_bs2, sh_bs3;
  __shared__ unsigned sh_bc2, sh_bc3;

  if (tid == 0) { sh_bs1 = 0.f; sh_bs2 = 0.f; sh_bs3 = 0.f; sh_bc2 = 0u; sh_bc3 = 0u; }
  if (tid < kInRow) sh_in[tid] = inputs[n * kInRow + tid];
  __syncthreads();

  // Obstacle precompute: center + (radius+OBST_RADIUS)^2, negative sentinel if
  // rr <= 0 (distance >= 0 can never be < a nonpositive radius).
  if (tid < kO) {
    float rr = sh_in[4 * kV + 3 * tid + 2] + kObstRadius;
    sh_ox[tid] = sh_in[4 * kV + 3 * tid + 0];
    sh_oy[tid] = sh_in[4 * kV + 3 * tid + 1];
    sh_orr2[tid] = (rr > 0.f) ? rr * rr : -1.0f;
  }

  // step = (cos, sin) * STEP; inclusive cumsum over h (128 = 2 waves).
  float theta = pred[(size_t)n * (kV * kH) + tid];
  float sv, cv;
  sincosf(theta, &sv, &cv);
  float cx = cv * kStep, sy = sv * kStep;
#pragma unroll
  for (int off = 1; off < 64; off <<= 1) {
    float pc = __shfl_up(cx, off, 64);
    float ps = __shfl_up(sy, off, 64);
    if (lane >= off) { cx += pc; sy += ps; }
  }
  if (h == 63) { sh_wc[v] = cx; sh_ws[v] = sy; }
  __syncthreads();  // also covers sh_ox/sh_oy/sh_orr2 writes above
  if (h >= 64) { cx += sh_wc[v]; sy += sh_ws[v]; }

  const float px = sh_in[4 * v + 0] + cx;
  const float py = sh_in[4 * v + 1] + sy;
  sh_traj[tid] = make_float2(px, py);

  // Term 1: distance to target.
  float dx = sh_in[4 * v + 2] - px;
  float dy = sh_in[4 * v + 3] - py;
  float s1 = sqrtf(dx * dx + dy * dy);

  // Term 2: masked mean of 1/dist over obstacles. mask: d2 < rr2  <=>  d < rr.
  float s2 = 0.f;
  unsigned c2 = 0;
#pragma unroll
  for (int o = 0; o < kO; ++o) {
    float ox = px - sh_ox[o];
    float oy = py - sh_oy[o];
    float d2 = ox * ox + oy * oy;
    if (d2 < sh_orr2[o]) { s2 += rsqrtf(d2); c2++; }
  }

  __syncthreads();  // sh_traj visible

  // Term 3: inter-vehicle distances (v vs v+1 at same h).
  float s3 = 0.f;
  unsigned c3 = 0;
  if (v < kV - 1) {
    float2 t2 = sh_traj[tid + kH];
    float ddx = t2.x - px, ddy = t2.y - py;
    float vd2 = ddx * ddx + ddy * ddy;
    if (vd2 < kVehRadius * kVehRadius) { s3 = rsqrtf(vd2); c3 = 1u; }
  }

  // Reduce 5 accumulators: wave shuffle-reduce, then LDS atomics, then global.
#pragma unroll
  for (int off = 32; off >= 1; off >>= 1) {
    s1 += __shfl_down(s1, off, 64);
    s2 += __shfl_down(s2, off, 64);
    s3 += __shfl_down(s3, off, 64);
    c2 += __shfl_down(c2, off, 64);
    c3 += __shfl_down(c3, off, 64);
  }
  if (lane == 0) {
    atomicAdd(&sh_bs1, s1);
    atomicAdd(&sh_bs2, s2);
    atomicAdd(&sh_bs3, s3);
    atomicAdd(&sh_bc2, c2);
    atomicAdd(&sh_bc3, c3);
  }
  __syncthreads();
  if (tid == 0) {
    atomicAdd(&accf[0], sh_bs1);
    atomicAdd(&accf[1], sh_bs2);
    atomicAdd(&accf[2], sh_bs3);
    atomicAdd(&accu[0], sh_bc2);
    atomicAdd(&accu[1], sh_bc3);
  }
}

__global__ void loss_final(const float* __restrict__ accf,
                           const unsigned* __restrict__ accu,
                           float* __restrict__ out) {
  float loss = accf[0] * (1.0f / (float)(kN * kV * kH)) * kDistCost;
  unsigned c2 = accu[0], c3 = accu[1];
  if (c2 > 0u) loss += (accf[1] / (float)c2) * kObstCost;
  if (c3 > 0u) loss += (accf[2] / (float)c3) * kVehCost;
  out[0] = loss;
}

extern "C" void kernel_launch(void* const* d_in, const int* in_sizes, int n_in,
                              void* d_out, int out_size, void* d_ws, size_t ws_size,
                              hipStream_t stream) {
  const float* pred = (const float*)d_in[0];     // (N, V, H, 1) f32
  const float* inputs = (const float*)d_in[1];   // (N, 80) f32
  float* accf = (float*)d_ws;                    // [s1, s2, s3]
  unsigned* accu = (unsigned*)((char*)d_ws + 3 * sizeof(float));  // [c2, c3]
  hipMemsetAsync(d_ws, 0, 32, stream);
  loss_main<<<kN, 1024, 0, stream>>>(pred, inputs, accf, accu);
  loss_final<<<1, 1, 0, stream>>>(accf, accu, (float*)d_out);
}

// Round 2
// 177.509 us; speedup vs baseline: 3.2398x; 3.2398x over previous
//
#include <hip/hip_runtime.h>

namespace {
constexpr int kN = 8192, kV = 8, kO = 16, kH = 128;
constexpr float kStep = 2.0f;
constexpr float kDistCost = 1.0f, kObstCost = 0.1f, kObstRadius = 1.0f;
constexpr float kVehCost = 0.1f, kVehRadius = 1.0f;
constexpr int kInRow = 4 * kV + 3 * kO;  // 80 floats per n
}  // namespace

// One block (1024 threads) per n. Thread tid = v*128 + h.
// Partials: 5 arrays of kN floats in d_ws (s1, s2, s3, c2, c3) — plain stores,
// no global atomics (R1 lesson: 40960 same-address atomics serialized ~500us).
__global__ __launch_bounds__(1024) void loss_main(
    const float* __restrict__ pred, const float* __restrict__ inputs,
    float* __restrict__ partials) {
  const int n = blockIdx.x;
  const int tid = threadIdx.x;
  const int v = tid >> 7;
  const int h = tid & (kH - 1);
  const int lane = tid & 63;

  __shared__ float sh_in[kInRow];
  __shared__ float sh_ox[kO], sh_oy[kO], sh_orr2[kO];
  __shared__ float2 sh_traj[kV * kH];
  __shared__ float sh_wc[kV], sh_ws[kV];
  __shared__ float sh_red[16][5];  // per-wave partials (16 waves)

  if (tid < kInRow) sh_in[tid] = inputs[n * kInRow + tid];
  __syncthreads();

  // Obstacle precompute: center + (radius+OBST_RADIUS)^2; negative sentinel if
  // rr <= 0 (d >= 0 can never be < a nonpositive radius).
  if (tid < kO) {
    float rr = sh_in[4 * kV + 3 * tid + 2] + kObstRadius;
    sh_ox[tid] = sh_in[4 * kV + 3 * tid + 0];
    sh_oy[tid] = sh_in[4 * kV + 3 * tid + 1];
    sh_orr2[tid] = (rr > 0.f) ? rr * rr : -1.0f;
  }

  // step = (cos, sin) * STEP via HW v_sin/v_cos; inclusive cumsum over h
  // (128 steps = 2 waves: shuffle-scan within wave, LDS fixup across).
  float theta = pred[(size_t)n * (kV * kH) + tid];
  float sv, cv;
  __sincosf(theta, &sv, &cv);
  float cx = cv * kStep, sy = sv * kStep;
#pragma unroll
  for (int off = 1; off < 64; off <<= 1) {
    float pc = __shfl_up(cx, off, 64);
    float ps = __shfl_up(sy, off, 64);
    if (lane >= off) { cx += pc; sy += ps; }
  }
  if (h == 63) { sh_wc[v] = cx; sh_ws[v] = sy; }
  __syncthreads();  // also covers sh_ox/sh_oy/sh_orr2 writes above
  if (h >= 64) { cx += sh_wc[v]; sy += sh_ws[v]; }

  const float px = sh_in[4 * v + 0] + cx;
  const float py = sh_in[4 * v + 1] + sy;
  sh_traj[tid] = make_float2(px, py);

  // Term 1: distance to target.
  float dx = sh_in[4 * v + 2] - px;
  float dy = sh_in[4 * v + 3] - py;
  float s1 = sqrtf(dx * dx + dy * dy);

  // Term 2: masked mean of 1/dist over obstacles (d2 < rr2 <=> d < rr).
  float s2 = 0.f, c2 = 0.f;
#pragma unroll
  for (int o = 0; o < kO; ++o) {
    float ox = px - sh_ox[o];
    float oy = py - sh_oy[o];
    float d2 = ox * ox + oy * oy;
    if (d2 < sh_orr2[o]) { s2 += rsqrtf(d2); c2 += 1.f; }
  }

  __syncthreads();  // sh_traj visible

  // Term 3: inter-vehicle distances (v vs v+1 at same h).
  float s3 = 0.f, c3 = 0.f;
  if (v < kV - 1) {
    float2 t2 = sh_traj[tid + kH];
    float ddx = t2.x - px, ddy = t2.y - py;
    float vd2 = ddx * ddx + ddy * ddy;
    if (vd2 < kVehRadius * kVehRadius) { s3 = rsqrtf(vd2); c3 = 1.f; }
  }

  // Wave shuffle-reduce 5 values, then cross-wave via LDS, then ONE store set.
#pragma unroll
  for (int off = 32; off >= 1; off >>= 1) {
    s1 += __shfl_down(s1, off, 64);
    s2 += __shfl_down(s2, off, 64);
    s3 += __shfl_down(s3, off, 64);
    c2 += __shfl_down(c2, off, 64);
    c3 += __shfl_down(c3, off, 64);
  }
  const int wave = tid >> 6;
  if (lane == 0) {
    sh_red[wave][0] = s1; sh_red[wave][1] = s2; sh_red[wave][2] = s3;
    sh_red[wave][3] = c2; sh_red[wave][4] = c3;
  }
  __syncthreads();
  if (tid < 5) {
    float acc = 0.f;
#pragma unroll
    for (int w = 0; w < 16; ++w) acc += sh_red[w][tid];
    partials[tid * kN + n] = acc;  // coalesced across blocks per-array
  }
}

// Single-block tree reduction over kN partials per accumulator.
__global__ __launch_bounds__(1024) void loss_final(
    const float* __restrict__ partials, float* __restrict__ out) {
  const int tid = threadIdx.x;
  const int lane = tid & 63;
  const int wave = tid >> 6;
  float acc[5];
#pragma unroll
  for (int a = 0; a < 5; ++a) {
    float s = 0.f;
    for (int i = tid; i < kN; i += 1024) s += partials[a * kN + i];
    acc[a] = s;
  }
#pragma unroll
  for (int off = 32; off >= 1; off >>= 1) {
#pragma unroll
    for (int a = 0; a < 5; ++a) acc[a] += __shfl_down(acc[a], off, 64);
  }
  __shared__ float sh[16][5];
  if (lane == 0) {
#pragma unroll
    for (int a = 0; a < 5; ++a) sh[wave][a] = acc[a];
  }
  __syncthreads();
  if (tid == 0) {
    float t[5];
#pragma unroll
    for (int a = 0; a < 5; ++a) {
      float s = 0.f;
#pragma unroll
      for (int w = 0; w < 16; ++w) s += sh[w][a];
      t[a] = s;
    }
    float loss = t[0] * (1.0f / (float)(kN * kV * kH)) * kDistCost;
    if (t[3] > 0.f) loss += (t[1] / t[3]) * kObstCost;
    if (t[4] > 0.f) loss += (t[2] / t[4]) * kVehCost;
    out[0] = loss;
  }
}

extern "C" void kernel_launch(void* const* d_in, const int* in_sizes, int n_in,
                              void* d_out, int out_size, void* d_ws, size_t ws_size,
                              hipStream_t stream) {
  const float* pred = (const float*)d_in[0];     // (N, V, H, 1) f32
  const float* inputs = (const float*)d_in[1];   // (N, 80) f32
  float* partials = (float*)d_ws;                // 5 * kN floats
  loss_main<<<kN, 1024, 0, stream>>>(pred, inputs, partials);
  loss_final<<<1, 1024, 0, stream>>>(partials, (float*)d_out);
}